// Round 20
// baseline (221.544 us; speedup 1.0000x reference)
//
#include <hip/hip_runtime.h>

#define N_NODES 100000
#define N_EDGES 1600000
#define IN_F 256
#define OUT_F 64
#define NPAD 100096
#define NB 391            // node buckets of 256 nodes
#define NBLK 512          // partition blocks
#define CHUNK 3125        // edges per partition block (512*3125 = 1.6M exact)
#define MSIZE (2*NB*NBLK) // dst matrix then src matrix = 400384
#define SC_BLOCKS 1564    // ceil(MSIZE/256)
#define CAP 12288         // LDS staging capacity per bucket (bucket_kernel)

typedef __attribute__((ext_vector_type(8))) _Float16 half8v;
typedef __attribute__((ext_vector_type(4))) float f32x4;

__device__ __forceinline__ unsigned short f2bf(float f) {
    unsigned u = __builtin_bit_cast(unsigned, f);
    return (unsigned short)((u + 0x7FFFu + ((u >> 16) & 1u)) >> 16);
}
__device__ __forceinline__ float bf2f(unsigned s) {
    return __builtin_bit_cast(float, s << 16);
}
__device__ __forceinline__ half8v cvt8(float4 x, float4 y) {
    half8v r;
    r[0] = (_Float16)x.x; r[1] = (_Float16)x.y; r[2] = (_Float16)x.z; r[3] = (_Float16)x.w;
    r[4] = (_Float16)y.x; r[5] = (_Float16)y.y; r[6] = (_Float16)y.z; r[7] = (_Float16)y.w;
    return r;
}

// --- per-block bucket histograms (dst and src); first 64 blocks also convert W;
//     block 0 zeroes the scan-done counter for this launch. ---
__global__ __launch_bounds__(256) void histA_kernel(const int* __restrict__ src,
                                                    const int* __restrict__ dst,
                                                    int* __restrict__ hist_g,
                                                    const float* __restrict__ W,
                                                    _Float16* __restrict__ Wt2,
                                                    int* __restrict__ done) {
    __shared__ int hD[NB], hS[NB];
    int b = blockIdx.x, t = threadIdx.x;
    if (b == 0 && t == 0) *done = 0;
    if (b < 64) {   // fused wsplit: W[k][c] -> lane-ordered fp16 Wt2
        int i = b * 256 + t;
        int k = i >> 6, c = i & 63;
        int ks4 = k >> 5, kin = k & 31, l4v = kin >> 3, kq = kin & 7;
        int cf  = c >> 4, l15v = c & 15;
        size_t idx = (((size_t)(ks4 * 4 + cf) * 64) + l4v * 16 + l15v) * 8 + kq;
        Wt2[idx] = (_Float16)W[i];
    }
    for (int j = t; j < NB; j += 256) { hD[j] = 0; hS[j] = 0; }
    __syncthreads();
    int e0 = b * CHUNK;
    for (int e = e0 + t; e < e0 + CHUNK; e += 256) {
        atomicAdd(&hD[dst[e] >> 8], 1);
        atomicAdd(&hS[src[e] >> 8], 1);
    }
    __syncthreads();
    for (int j = t; j < NB; j += 256) {
        hist_g[j * NBLK + b] = hD[j];
        hist_g[NB * NBLK + j * NBLK + b] = hS[j];
    }
}

// --- scan of hist_g[MSIZE] (block-local) + fused partials-scan in the LAST block
//     to finish (deterministic last-block pattern; no separate scan2 launch). ---
__global__ __launch_bounds__(256) void scan1_kernel(int* __restrict__ data,
                                                    int* __restrict__ partials,
                                                    int* __restrict__ done) {
    __shared__ int sm[256];
    __shared__ int isLast;
    int t = threadIdx.x;
    int i = blockIdx.x * 256 + t;
    int v = (i < MSIZE) ? data[i] : 0;
    sm[t] = v;
    __syncthreads();
    int x = v;
    #pragma unroll
    for (int off = 1; off < 256; off <<= 1) {
        int tv = 0;
        if (t >= off) tv = sm[t - off];
        __syncthreads();
        x += tv;
        sm[t] = x;
        __syncthreads();
    }
    if (i < MSIZE) data[i] = x - v;
    if (t == 255) partials[blockIdx.x] = x;

    // last-block: scan partials[SC_BLOCKS] (7 elems/thread)
    __threadfence();
    if (t == 0) {
        int prev = atomicAdd(done, 1);
        isLast = (prev == SC_BLOCKS - 1) ? 1 : 0;
    }
    __syncthreads();
    if (isLast) {
        __threadfence();
        int base = t * 7;
        int loc[7];
        int sum = 0;
        #pragma unroll
        for (int q = 0; q < 7; ++q) {
            int idx = base + q;
            int pv = (idx < SC_BLOCKS) ? partials[idx] : 0;
            loc[q] = sum;
            sum += pv;
        }
        sm[t] = sum;
        __syncthreads();
        int x2 = sum;
        #pragma unroll
        for (int off = 1; off < 256; off <<= 1) {
            int tv = (t >= off) ? sm[t - off] : 0;
            __syncthreads();
            x2 += tv;
            sm[t] = x2;
            __syncthreads();
        }
        int excl = x2 - sum;
        #pragma unroll
        for (int q = 0; q < 7; ++q) {
            int idx = base + q;
            if (idx < SC_BLOCKS) partials[idx] = excl + loc[q];
        }
    }
}

// global scanned value at flat index idx (after scan1)
__device__ __forceinline__ int gscan(const int* __restrict__ hist_g,
                                     const int* __restrict__ partials, int idx) {
    return hist_g[idx] + partials[idx >> 8];
}

// --- partition: LDS-stage then CONTIGUOUS write-out; bucket id in u16 side-array;
//     write base pre-folded (baseX[j] -= L[j]) so write-out is baseX'[bkt]+i.
__global__ __launch_bounds__(256) void part_kernel(const int* __restrict__ src,
                                                   const int* __restrict__ dst,
                                                   const int* __restrict__ hist_g,
                                                   const int* __restrict__ partials,
                                                   unsigned* __restrict__ edge_buf,
                                                   int* __restrict__ src_part) {
    __shared__ unsigned stageA[CHUNK], stageB[CHUNK];
    __shared__ unsigned short bkt[CHUNK];
    __shared__ int L[512], cur[512];
    __shared__ int baseD[NB], baseS[NB];
    const int b = blockIdx.x, t = threadIdx.x;
    const int e0 = b * CHUNK;

    // thread t owns indices t and t+256 of baseD/baseS/L/cur throughout
    if (t < NB)       baseD[t]       = gscan(hist_g, partials, t * NBLK + b);
    if (t + 256 < NB) baseD[t + 256] = gscan(hist_g, partials, (t + 256) * NBLK + b);
    if (t < NB)       baseS[t]       = gscan(hist_g, partials, NB * NBLK + t * NBLK + b) - N_EDGES;
    if (t + 256 < NB) baseS[t + 256] = gscan(hist_g, partials, NB * NBLK + (t + 256) * NBLK + b) - N_EDGES;

    // ---------- phase A: dst stream ----------
    L[t] = 0; L[t + 256] = 0;
    __syncthreads();
    for (int i = t; i < CHUNK; i += 256) {
        int d = dst[e0 + i];
        stageA[i] = (unsigned)d;
        atomicAdd(&L[d >> 8], 1);
    }
    __syncthreads();
    int v0 = L[t], v1 = L[t + 256];
    #pragma unroll
    for (int off = 1; off < 512; off <<= 1) {
        int a0 = (t >= off) ? L[t - off] : 0;
        int a1 = (t + 256 >= off) ? L[t + 256 - off] : 0;
        __syncthreads();
        L[t] += a0; L[t + 256] += a1;
        __syncthreads();
    }
    {
        int i0 = L[t], i1 = L[t + 256];
        __syncthreads();
        int e0x = i0 - v0, e1x = i1 - v1;          // exclusive
        L[t] = e0x;  L[t + 256] = e1x;
        cur[t] = e0x; cur[t + 256] = e1x;
        if (t < NB)       baseD[t]       -= e0x;   // fold -L into base
        if (t + 256 < NB) baseD[t + 256] -= e1x;
    }
    __syncthreads();
    for (int i = t; i < CHUNK; i += 256) {
        int d = (int)stageA[i];
        int s = src[e0 + i];
        stageA[i] = (unsigned)s;                   // stash src for phase B
        int bj = d >> 8;
        int pos = atomicAdd(&cur[bj], 1);
        stageB[pos] = ((unsigned)(d & 255) << 17) | (unsigned)s;
        bkt[pos] = (unsigned short)bj;
    }
    __syncthreads();
    for (int i = t; i < CHUNK; i += 256)
        edge_buf[baseD[bkt[i]] + i] = stageB[i];
    __syncthreads();

    // ---------- phase B: src stream (from stashed stageA) ----------
    L[t] = 0; L[t + 256] = 0;
    __syncthreads();
    for (int i = t; i < CHUNK; i += 256)
        atomicAdd(&L[stageA[i] >> 8], 1);
    __syncthreads();
    v0 = L[t]; v1 = L[t + 256];
    #pragma unroll
    for (int off = 1; off < 512; off <<= 1) {
        int a0 = (t >= off) ? L[t - off] : 0;
        int a1 = (t + 256 >= off) ? L[t + 256 - off] : 0;
        __syncthreads();
        L[t] += a0; L[t + 256] += a1;
        __syncthreads();
    }
    {
        int i0 = L[t], i1 = L[t + 256];
        __syncthreads();
        int e0x = i0 - v0, e1x = i1 - v1;
        L[t] = e0x;  L[t + 256] = e1x;
        cur[t] = e0x; cur[t + 256] = e1x;
        if (t < NB)       baseS[t]       -= e0x;
        if (t + 256 < NB) baseS[t + 256] -= e1x;
    }
    __syncthreads();
    for (int i = t; i < CHUNK; i += 256) {
        unsigned s = stageA[i];
        int bj = (int)(s >> 8);
        int pos = atomicAdd(&cur[bj], 1);
        stageB[pos] = s;
        bkt[pos] = (unsigned short)bj;
    }
    __syncthreads();
    for (int i = t; i < CHUNK; i += 256)
        src_part[baseS[bkt[i]] + i] = (int)stageB[i];
}

// --- per-bucket: in-LDS counting sort of dst edges -> CSR (in place) + row_ptr,
//     then (fused) out-degree histogram of src_part -> norm_out. ---
__global__ __launch_bounds__(256) void bucket_kernel(unsigned* __restrict__ edge_buf,
                                                     const int* __restrict__ hist_g,
                                                     const int* __restrict__ partials,
                                                     int* __restrict__ row_ptr,
                                                     const int* __restrict__ src_part,
                                                     float* __restrict__ norm_out) {
    __shared__ unsigned stage[CAP];
    __shared__ int hist[256];
    __shared__ int cur[256];
    int j = blockIdx.x, t = threadIdx.x;
    int b0 = gscan(hist_g, partials, j * NBLK);
    int b1 = (j + 1 < NB) ? gscan(hist_g, partials, (j + 1) * NBLK) : N_EDGES;
    int cnt = b1 - b0;
    hist[t] = 0;
    __syncthreads();
    for (int i = t; i < cnt; i += 256) {
        unsigned p = edge_buf[b0 + i];
        stage[i] = p;
        atomicAdd(&hist[p >> 17], 1);
    }
    __syncthreads();
    int v = hist[t];
    cur[t] = v;
    __syncthreads();
    int x = v;
    #pragma unroll
    for (int off = 1; off < 256; off <<= 1) {
        int tv = (t >= off) ? cur[t - off] : 0;
        __syncthreads();
        x += tv;
        cur[t] = x;
        __syncthreads();
    }
    int excl = x - v;
    row_ptr[j * 256 + t] = b0 + excl;
    cur[t] = excl;
    __syncthreads();
    for (int i = t; i < cnt; i += 256) {
        unsigned p = stage[i];
        int pos = atomicAdd(&cur[p >> 17], 1);
        edge_buf[b0 + pos] = p & 0x1FFFFu;
    }
    // ---- fused normout ----
    __syncthreads();
    hist[t] = 0;
    __syncthreads();
    int s0 = gscan(hist_g, partials, NB * NBLK + j * NBLK) - N_EDGES;
    int s1 = (j + 1 < NB) ? gscan(hist_g, partials, NB * NBLK + (j + 1) * NBLK) - N_EDGES
                          : N_EDGES;
    for (int e = s0 + t; e < s1; e += 256)
        atomicAdd(&hist[src_part[e] & 255], 1);
    __syncthreads();
    int node = j * 256 + t;
    if (node < N_NODES) {
        int d = hist[t]; if (d < 1) d = 1;
        norm_out[node] = rsqrtf((float)d);
    }
}

// --- MFMA GEMM (fp16 single-MFMA): h[r][c] = (sum_k feat[r][k]*W[k][c]) * norm_out[r].
//     B staged once per block in LDS; h stored bf16 [node][64]. ---
__global__ __launch_bounds__(256) void gemm_kernel(const float* __restrict__ feat,
                                                   const _Float16* __restrict__ Wt2,
                                                   const float* __restrict__ norm_out,
                                                   unsigned short* __restrict__ h) {
    __shared__ _Float16 Bs[16384];   // 32 KB, lane-ordered like Wt2
    const int tid  = threadIdx.x;
    const int wave = tid >> 6, lane = tid & 63;
    const int l15  = lane & 15, l4 = lane >> 4;
    const int rw0  = blockIdx.x * 128 + wave * 32;

    #pragma unroll
    for (int i = 0; i < 8; ++i) {
        const int fr = i * 4 + wave;
        const _Float16* gsrc = Wt2 + ((size_t)fr * 64 + lane) * 8;
        _Float16* ldst = &Bs[(size_t)fr * 64 * 8];
        __builtin_amdgcn_global_load_lds(
            (const __attribute__((address_space(1))) void*)gsrc,
            (__attribute__((address_space(3))) void*)ldst, 16, 0, 0);
    }

    int r0 = rw0 + l15;
    int r1 = r0 + 16;
    int r0c = r0 < N_NODES ? r0 : 0;
    int r1c = r1 < N_NODES ? r1 : 0;
    const float* pA0 = feat + (size_t)r0c * IN_F + l4 * 8;
    const float* pA1 = feat + (size_t)r1c * IN_F + l4 * 8;

    f32x4 acc[2][4];
    #pragma unroll
    for (int rf = 0; rf < 2; ++rf)
        #pragma unroll
        for (int cf = 0; cf < 4; ++cf)
            acc[rf][cf] = (f32x4){0.f, 0.f, 0.f, 0.f};

    float4 nx0 = *(const float4*)(pA0);
    float4 ny0 = *(const float4*)(pA0 + 4);
    float4 nx1 = *(const float4*)(pA1);
    float4 ny1 = *(const float4*)(pA1 + 4);

    __syncthreads();

    #pragma unroll
    for (int ks4 = 0; ks4 < 8; ++ks4) {
        float4 cx0 = nx0, cy0 = ny0, cx1 = nx1, cy1 = ny1;
        if (ks4 < 7) {
            nx0 = *(const float4*)(pA0 + 32 * (ks4 + 1));
            ny0 = *(const float4*)(pA0 + 32 * (ks4 + 1) + 4);
            nx1 = *(const float4*)(pA1 + 32 * (ks4 + 1));
            ny1 = *(const float4*)(pA1 + 32 * (ks4 + 1) + 4);
        }
        half8v bfr[4];
        #pragma unroll
        for (int cf = 0; cf < 4; ++cf)
            bfr[cf] = *(const half8v*)&Bs[(((size_t)(ks4 * 4 + cf) * 64) + lane) * 8];
        half8v a0 = cvt8(cx0, cy0);
        half8v a1 = cvt8(cx1, cy1);
        #pragma unroll
        for (int cf = 0; cf < 4; ++cf) {
            acc[0][cf] = __builtin_amdgcn_mfma_f32_16x16x32_f16(a0, bfr[cf], acc[0][cf], 0, 0, 0);
            acc[1][cf] = __builtin_amdgcn_mfma_f32_16x16x32_f16(a1, bfr[cf], acc[1][cf], 0, 0, 0);
        }
    }

    #pragma unroll
    for (int rf = 0; rf < 2; ++rf) {
        #pragma unroll
        for (int r = 0; r < 4; ++r) {
            int row = rw0 + rf * 16 + l4 * 4 + r;
            if (row < N_NODES) {
                float s = norm_out[row];
                #pragma unroll
                for (int cf = 0; cf < 4; ++cf)
                    h[(size_t)row * OUT_F + cf * 16 + l15] = f2bf(acc[rf][cf][r] * s);
            }
        }
    }
}

// --- aggregate: one wave per dst node; 32 edges per iteration via FOUR independent
//     id-load + uint4-gather chains (deep MLP).  Branchless clamp+mask. ---
__global__ __launch_bounds__(256) void agg_kernel(const int* __restrict__ row_ptr,
                                                  const unsigned* __restrict__ edge_src,
                                                  const unsigned short* __restrict__ h,
                                                  const float* __restrict__ bias,
                                                  float* __restrict__ out) {
    int wid  = (blockIdx.x * 256 + threadIdx.x) >> 6;
    int lane = threadIdx.x & 63;
    if (wid >= N_NODES) return;
    int g  = lane >> 3;
    int fp = lane & 7;
    int start = row_ptr[wid];
    int end   = row_ptr[wid + 1];
    int deg   = end - start;

    float a[8];
    #pragma unroll
    for (int i = 0; i < 8; ++i) a[i] = 0.f;

    for (int e = start; e < end; e += 32) {
        int ee0 = e + g, ee1 = ee0 + 8, ee2 = ee0 + 16, ee3 = ee0 + 24;
        int id0 = (ee0 < end) ? (int)edge_src[ee0] : -1;
        int id1 = (ee1 < end) ? (int)edge_src[ee1] : -1;
        int id2 = (ee2 < end) ? (int)edge_src[ee2] : -1;
        int id3 = (ee3 < end) ? (int)edge_src[ee3] : -1;
        int s0 = id0 >= 0 ? id0 : 0;
        int s1 = id1 >= 0 ? id1 : 0;
        int s2 = id2 >= 0 ? id2 : 0;
        int s3 = id3 >= 0 ? id3 : 0;
        uint4 w0 = *(const uint4*)&h[(size_t)s0 * OUT_F + fp * 8];
        uint4 w1 = *(const uint4*)&h[(size_t)s1 * OUT_F + fp * 8];
        uint4 w2 = *(const uint4*)&h[(size_t)s2 * OUT_F + fp * 8];
        uint4 w3 = *(const uint4*)&h[(size_t)s3 * OUT_F + fp * 8];
        if (id0 < 0) { w0.x = 0u; w0.y = 0u; w0.z = 0u; w0.w = 0u; }
        if (id1 < 0) { w1.x = 0u; w1.y = 0u; w1.z = 0u; w1.w = 0u; }
        if (id2 < 0) { w2.x = 0u; w2.y = 0u; w2.z = 0u; w2.w = 0u; }
        if (id3 < 0) { w3.x = 0u; w3.y = 0u; w3.z = 0u; w3.w = 0u; }
        a[0] += bf2f(w0.x & 0xFFFFu); a[1] += bf2f(w0.x >> 16);
        a[2] += bf2f(w0.y & 0xFFFFu); a[3] += bf2f(w0.y >> 16);
        a[4] += bf2f(w0.z & 0xFFFFu); a[5] += bf2f(w0.z >> 16);
        a[6] += bf2f(w0.w & 0xFFFFu); a[7] += bf2f(w0.w >> 16);
        a[0] += bf2f(w1.x & 0xFFFFu); a[1] += bf2f(w1.x >> 16);
        a[2] += bf2f(w1.y & 0xFFFFu); a[3] += bf2f(w1.y >> 16);
        a[4] += bf2f(w1.z & 0xFFFFu); a[5] += bf2f(w1.z >> 16);
        a[6] += bf2f(w1.w & 0xFFFFu); a[7] += bf2f(w1.w >> 16);
        a[0] += bf2f(w2.x & 0xFFFFu); a[1] += bf2f(w2.x >> 16);
        a[2] += bf2f(w2.y & 0xFFFFu); a[3] += bf2f(w2.y >> 16);
        a[4] += bf2f(w2.z & 0xFFFFu); a[5] += bf2f(w2.z >> 16);
        a[6] += bf2f(w2.w & 0xFFFFu); a[7] += bf2f(w2.w >> 16);
        a[0] += bf2f(w3.x & 0xFFFFu); a[1] += bf2f(w3.x >> 16);
        a[2] += bf2f(w3.y & 0xFFFFu); a[3] += bf2f(w3.y >> 16);
        a[4] += bf2f(w3.z & 0xFFFFu); a[5] += bf2f(w3.z >> 16);
        a[6] += bf2f(w3.w & 0xFFFFu); a[7] += bf2f(w3.w >> 16);
    }

    #pragma unroll
    for (int off = 8; off < 64; off <<= 1) {
        #pragma unroll
        for (int i = 0; i < 8; ++i) a[i] += __shfl_xor(a[i], off);
    }

    if (g == 0) {
        int dc = deg < 1 ? 1 : deg;
        float nrm = rsqrtf((float)dc);
        float4 b0 = *(const float4*)&bias[fp * 8];
        float4 b1 = *(const float4*)&bias[fp * 8 + 4];
        float4 r0, r1;
        r0.x = fmaxf(a[0] * nrm + b0.x, 0.f);
        r0.y = fmaxf(a[1] * nrm + b0.y, 0.f);
        r0.z = fmaxf(a[2] * nrm + b0.z, 0.f);
        r0.w = fmaxf(a[3] * nrm + b0.w, 0.f);
        r1.x = fmaxf(a[4] * nrm + b1.x, 0.f);
        r1.y = fmaxf(a[5] * nrm + b1.y, 0.f);
        r1.z = fmaxf(a[6] * nrm + b1.z, 0.f);
        r1.w = fmaxf(a[7] * nrm + b1.w, 0.f);
        *(float4*)&out[(size_t)wid * OUT_F + fp * 8]     = r0;
        *(float4*)&out[(size_t)wid * OUT_F + fp * 8 + 4] = r1;
    }
}

extern "C" void kernel_launch(void* const* d_in, const int* in_sizes, int n_in,
                              void* d_out, int out_size, void* d_ws, size_t ws_size,
                              hipStream_t stream) {
    const float* feat = (const float*)d_in[0];
    const float* W    = (const float*)d_in[1];
    const float* bias = (const float*)d_in[2];
    const int*   src  = (const int*)d_in[3];
    const int*   dst  = (const int*)d_in[4];
    float* out = (float*)d_out;

    char* w = (char*)d_ws;
    size_t off = 0;
    auto take = [&](size_t bytes) { char* p = w + off; off += (bytes + 255) & ~(size_t)255; return p; };

    int*            hist_g   = (int*)take((size_t)MSIZE * 4);
    int*            partials = (int*)take((size_t)SC_BLOCKS * 4);
    int*            done     = (int*)take(256);
    float*          norm_out = (float*)take((size_t)NPAD * 4);
    int*            row_ptr  = (int*)take((size_t)(NPAD + 64) * 4);
    _Float16*       Wt2      = (_Float16*)take((size_t)IN_F * OUT_F * 2);   // 32 KB
    unsigned*       edge_buf = (unsigned*)take((size_t)N_EDGES * 4);
    unsigned short* h        = (unsigned short*)take((size_t)NPAD * OUT_F * 2);
    int*            src_part = (int*)take((size_t)N_EDGES * 4);

    histA_kernel<<<NBLK, 256, 0, stream>>>(src, dst, hist_g, W, Wt2, done);
    scan1_kernel<<<SC_BLOCKS, 256, 0, stream>>>(hist_g, partials, done);
    part_kernel<<<NBLK, 256, 0, stream>>>(src, dst, hist_g, partials, edge_buf, src_part);
    bucket_kernel<<<NB, 256, 0, stream>>>(edge_buf, hist_g, partials, row_ptr, src_part, norm_out);
    gemm_kernel<<<(NPAD / 128), 256, 0, stream>>>(feat, Wt2, norm_out, h);
    agg_kernel<<<(N_NODES * 64 + 255) / 256, 256, 0, stream>>>(row_ptr, edge_buf, h, bias, out);
}

// Round 21
// 123.046 us; speedup vs baseline: 1.8005x; 1.8005x over previous
//
#include <hip/hip_runtime.h>

#define N_NODES 100000
#define N_EDGES 1600000
#define IN_F 256
#define OUT_F 64
#define NPAD 100096
#define NB 391            // node buckets of 256 nodes
#define NBLK 512          // partition blocks
#define CHUNK 3125        // edges per partition block (512*3125 = 1.6M exact)
#define MSIZE (2*NB*NBLK) // dst matrix then src matrix = 400384
#define SC_BLOCKS 1564    // ceil(MSIZE/256)
#define CAP 12288         // LDS staging capacity per bucket (bucket_kernel)

typedef __attribute__((ext_vector_type(8))) _Float16 half8v;
typedef __attribute__((ext_vector_type(4))) float f32x4;

__device__ __forceinline__ unsigned short f2bf(float f) {
    unsigned u = __builtin_bit_cast(unsigned, f);
    return (unsigned short)((u + 0x7FFFu + ((u >> 16) & 1u)) >> 16);
}
__device__ __forceinline__ float bf2f(unsigned s) {
    return __builtin_bit_cast(float, s << 16);
}
__device__ __forceinline__ half8v cvt8(float4 x, float4 y) {
    half8v r;
    r[0] = (_Float16)x.x; r[1] = (_Float16)x.y; r[2] = (_Float16)x.z; r[3] = (_Float16)x.w;
    r[4] = (_Float16)y.x; r[5] = (_Float16)y.y; r[6] = (_Float16)y.z; r[7] = (_Float16)y.w;
    return r;
}

// --- per-block bucket histograms (dst and src); first 64 blocks also convert W ---
__global__ __launch_bounds__(256) void histA_kernel(const int* __restrict__ src,
                                                    const int* __restrict__ dst,
                                                    int* __restrict__ hist_g,
                                                    const float* __restrict__ W,
                                                    _Float16* __restrict__ Wt2) {
    __shared__ int hD[NB], hS[NB];
    int b = blockIdx.x, t = threadIdx.x;
    if (b < 64) {   // fused wsplit: W[k][c] -> lane-ordered fp16 Wt2
        int i = b * 256 + t;
        int k = i >> 6, c = i & 63;
        int ks4 = k >> 5, kin = k & 31, l4v = kin >> 3, kq = kin & 7;
        int cf  = c >> 4, l15v = c & 15;
        size_t idx = (((size_t)(ks4 * 4 + cf) * 64) + l4v * 16 + l15v) * 8 + kq;
        Wt2[idx] = (_Float16)W[i];
    }
    for (int j = t; j < NB; j += 256) { hD[j] = 0; hS[j] = 0; }
    __syncthreads();
    int e0 = b * CHUNK;
    for (int e = e0 + t; e < e0 + CHUNK; e += 256) {
        atomicAdd(&hD[dst[e] >> 8], 1);
        atomicAdd(&hS[src[e] >> 8], 1);
    }
    __syncthreads();
    for (int j = t; j < NB; j += 256) {
        hist_g[j * NBLK + b] = hD[j];
        hist_g[NB * NBLK + j * NBLK + b] = hS[j];
    }
}

// --- exclusive scan of hist_g[MSIZE]: block-local scan + block partials ---
__global__ __launch_bounds__(256) void scan1_kernel(int* __restrict__ data,
                                                    int* __restrict__ partials) {
    __shared__ int sm[256];
    int i = blockIdx.x * 256 + threadIdx.x;
    int v = (i < MSIZE) ? data[i] : 0;
    sm[threadIdx.x] = v;
    __syncthreads();
    int x = v;
    #pragma unroll
    for (int off = 1; off < 256; off <<= 1) {
        int tv = 0;
        if ((int)threadIdx.x >= off) tv = sm[threadIdx.x - off];
        __syncthreads();
        x += tv;
        sm[threadIdx.x] = x;
        __syncthreads();
    }
    if (i < MSIZE) data[i] = x - v;
    if (threadIdx.x == 255) partials[blockIdx.x] = x;
}

// 2 elements per thread (SC_BLOCKS up to 2048)
__global__ __launch_bounds__(1024) void scan2_kernel(int* __restrict__ partials) {
    __shared__ int sm[1024];
    int i = threadIdx.x;
    int v0 = (2 * i     < SC_BLOCKS) ? partials[2 * i]     : 0;
    int v1 = (2 * i + 1 < SC_BLOCKS) ? partials[2 * i + 1] : 0;
    int pv = v0 + v1;
    sm[i] = pv;
    __syncthreads();
    int x = pv;
    #pragma unroll
    for (int off = 1; off < 1024; off <<= 1) {
        int tv = (i >= off) ? sm[i - off] : 0;
        __syncthreads();
        x += tv;
        sm[i] = x;
        __syncthreads();
    }
    int excl = x - pv;
    if (2 * i     < SC_BLOCKS) partials[2 * i]     = excl;
    if (2 * i + 1 < SC_BLOCKS) partials[2 * i + 1] = excl + v0;
}

// global scanned value at flat index idx (after scan1+scan2)
__device__ __forceinline__ int gscan(const int* __restrict__ hist_g,
                                     const int* __restrict__ partials, int idx) {
    return hist_g[idx] + partials[idx >> 8];
}

// --- partition: LDS-stage then CONTIGUOUS write-out; bucket id in u16 side-array;
//     write base pre-folded (baseX[j] -= L[j]) so write-out is baseX'[bkt]+i.
__global__ __launch_bounds__(256) void part_kernel(const int* __restrict__ src,
                                                   const int* __restrict__ dst,
                                                   const int* __restrict__ hist_g,
                                                   const int* __restrict__ partials,
                                                   unsigned* __restrict__ edge_buf,
                                                   int* __restrict__ src_part) {
    __shared__ unsigned stageA[CHUNK], stageB[CHUNK];
    __shared__ unsigned short bkt[CHUNK];
    __shared__ int L[512], cur[512];
    __shared__ int baseD[NB], baseS[NB];
    const int b = blockIdx.x, t = threadIdx.x;
    const int e0 = b * CHUNK;

    // thread t owns indices t and t+256 of baseD/baseS/L/cur throughout
    if (t < NB)       baseD[t]       = gscan(hist_g, partials, t * NBLK + b);
    if (t + 256 < NB) baseD[t + 256] = gscan(hist_g, partials, (t + 256) * NBLK + b);
    if (t < NB)       baseS[t]       = gscan(hist_g, partials, NB * NBLK + t * NBLK + b) - N_EDGES;
    if (t + 256 < NB) baseS[t + 256] = gscan(hist_g, partials, NB * NBLK + (t + 256) * NBLK + b) - N_EDGES;

    // ---------- phase A: dst stream ----------
    L[t] = 0; L[t + 256] = 0;
    __syncthreads();
    for (int i = t; i < CHUNK; i += 256) {
        int d = dst[e0 + i];
        stageA[i] = (unsigned)d;
        atomicAdd(&L[d >> 8], 1);
    }
    __syncthreads();
    int v0 = L[t], v1 = L[t + 256];
    #pragma unroll
    for (int off = 1; off < 512; off <<= 1) {
        int a0 = (t >= off) ? L[t - off] : 0;
        int a1 = (t + 256 >= off) ? L[t + 256 - off] : 0;
        __syncthreads();
        L[t] += a0; L[t + 256] += a1;
        __syncthreads();
    }
    {
        int i0 = L[t], i1 = L[t + 256];
        __syncthreads();
        int e0x = i0 - v0, e1x = i1 - v1;          // exclusive
        L[t] = e0x;  L[t + 256] = e1x;
        cur[t] = e0x; cur[t + 256] = e1x;
        if (t < NB)       baseD[t]       -= e0x;   // fold -L into base
        if (t + 256 < NB) baseD[t + 256] -= e1x;
    }
    __syncthreads();
    for (int i = t; i < CHUNK; i += 256) {
        int d = (int)stageA[i];
        int s = src[e0 + i];
        stageA[i] = (unsigned)s;                   // stash src for phase B
        int bj = d >> 8;
        int pos = atomicAdd(&cur[bj], 1);
        stageB[pos] = ((unsigned)(d & 255) << 17) | (unsigned)s;
        bkt[pos] = (unsigned short)bj;
    }
    __syncthreads();
    for (int i = t; i < CHUNK; i += 256)
        edge_buf[baseD[bkt[i]] + i] = stageB[i];
    __syncthreads();

    // ---------- phase B: src stream (from stashed stageA) ----------
    L[t] = 0; L[t + 256] = 0;
    __syncthreads();
    for (int i = t; i < CHUNK; i += 256)
        atomicAdd(&L[stageA[i] >> 8], 1);
    __syncthreads();
    v0 = L[t]; v1 = L[t + 256];
    #pragma unroll
    for (int off = 1; off < 512; off <<= 1) {
        int a0 = (t >= off) ? L[t - off] : 0;
        int a1 = (t + 256 >= off) ? L[t + 256 - off] : 0;
        __syncthreads();
        L[t] += a0; L[t + 256] += a1;
        __syncthreads();
    }
    {
        int i0 = L[t], i1 = L[t + 256];
        __syncthreads();
        int e0x = i0 - v0, e1x = i1 - v1;
        L[t] = e0x;  L[t + 256] = e1x;
        cur[t] = e0x; cur[t + 256] = e1x;
        if (t < NB)       baseS[t]       -= e0x;
        if (t + 256 < NB) baseS[t + 256] -= e1x;
    }
    __syncthreads();
    for (int i = t; i < CHUNK; i += 256) {
        unsigned s = stageA[i];
        int bj = (int)(s >> 8);
        int pos = atomicAdd(&cur[bj], 1);
        stageB[pos] = s;
        bkt[pos] = (unsigned short)bj;
    }
    __syncthreads();
    for (int i = t; i < CHUNK; i += 256)
        src_part[baseS[bkt[i]] + i] = (int)stageB[i];
}

// --- per-bucket: in-LDS counting sort of dst edges -> CSR (in place) + row_ptr,
//     then (fused) out-degree histogram of src_part -> norm_out. ---
__global__ __launch_bounds__(256) void bucket_kernel(unsigned* __restrict__ edge_buf,
                                                     const int* __restrict__ hist_g,
                                                     const int* __restrict__ partials,
                                                     int* __restrict__ row_ptr,
                                                     const int* __restrict__ src_part,
                                                     float* __restrict__ norm_out) {
    __shared__ unsigned stage[CAP];
    __shared__ int hist[256];
    __shared__ int cur[256];
    int j = blockIdx.x, t = threadIdx.x;
    int b0 = gscan(hist_g, partials, j * NBLK);
    int b1 = (j + 1 < NB) ? gscan(hist_g, partials, (j + 1) * NBLK) : N_EDGES;
    int cnt = b1 - b0;
    hist[t] = 0;
    __syncthreads();
    for (int i = t; i < cnt; i += 256) {
        unsigned p = edge_buf[b0 + i];
        stage[i] = p;
        atomicAdd(&hist[p >> 17], 1);
    }
    __syncthreads();
    int v = hist[t];
    cur[t] = v;
    __syncthreads();
    int x = v;
    #pragma unroll
    for (int off = 1; off < 256; off <<= 1) {
        int tv = (t >= off) ? cur[t - off] : 0;
        __syncthreads();
        x += tv;
        cur[t] = x;
        __syncthreads();
    }
    int excl = x - v;
    row_ptr[j * 256 + t] = b0 + excl;
    cur[t] = excl;
    __syncthreads();
    for (int i = t; i < cnt; i += 256) {
        unsigned p = stage[i];
        int pos = atomicAdd(&cur[p >> 17], 1);
        edge_buf[b0 + pos] = p & 0x1FFFFu;
    }
    // ---- fused normout ----
    __syncthreads();
    hist[t] = 0;
    __syncthreads();
    int s0 = gscan(hist_g, partials, NB * NBLK + j * NBLK) - N_EDGES;
    int s1 = (j + 1 < NB) ? gscan(hist_g, partials, NB * NBLK + (j + 1) * NBLK) - N_EDGES
                          : N_EDGES;
    for (int e = s0 + t; e < s1; e += 256)
        atomicAdd(&hist[src_part[e] & 255], 1);
    __syncthreads();
    int node = j * 256 + t;
    if (node < N_NODES) {
        int d = hist[t]; if (d < 1) d = 1;
        norm_out[node] = rsqrtf((float)d);
    }
}

// --- MFMA GEMM (fp16 single-MFMA): h[r][c] = (sum_k feat[r][k]*W[k][c]) * norm_out[r].
//     B staged once per block in LDS; h stored bf16 [node][64]. ---
__global__ __launch_bounds__(256) void gemm_kernel(const float* __restrict__ feat,
                                                   const _Float16* __restrict__ Wt2,
                                                   const float* __restrict__ norm_out,
                                                   unsigned short* __restrict__ h) {
    __shared__ _Float16 Bs[16384];   // 32 KB, lane-ordered like Wt2
    const int tid  = threadIdx.x;
    const int wave = tid >> 6, lane = tid & 63;
    const int l15  = lane & 15, l4 = lane >> 4;
    const int rw0  = blockIdx.x * 128 + wave * 32;

    #pragma unroll
    for (int i = 0; i < 8; ++i) {
        const int fr = i * 4 + wave;
        const _Float16* gsrc = Wt2 + ((size_t)fr * 64 + lane) * 8;
        _Float16* ldst = &Bs[(size_t)fr * 64 * 8];
        __builtin_amdgcn_global_load_lds(
            (const __attribute__((address_space(1))) void*)gsrc,
            (__attribute__((address_space(3))) void*)ldst, 16, 0, 0);
    }

    int r0 = rw0 + l15;
    int r1 = r0 + 16;
    int r0c = r0 < N_NODES ? r0 : 0;
    int r1c = r1 < N_NODES ? r1 : 0;
    const float* pA0 = feat + (size_t)r0c * IN_F + l4 * 8;
    const float* pA1 = feat + (size_t)r1c * IN_F + l4 * 8;

    f32x4 acc[2][4];
    #pragma unroll
    for (int rf = 0; rf < 2; ++rf)
        #pragma unroll
        for (int cf = 0; cf < 4; ++cf)
            acc[rf][cf] = (f32x4){0.f, 0.f, 0.f, 0.f};

    float4 nx0 = *(const float4*)(pA0);
    float4 ny0 = *(const float4*)(pA0 + 4);
    float4 nx1 = *(const float4*)(pA1);
    float4 ny1 = *(const float4*)(pA1 + 4);

    __syncthreads();

    #pragma unroll
    for (int ks4 = 0; ks4 < 8; ++ks4) {
        float4 cx0 = nx0, cy0 = ny0, cx1 = nx1, cy1 = ny1;
        if (ks4 < 7) {
            nx0 = *(const float4*)(pA0 + 32 * (ks4 + 1));
            ny0 = *(const float4*)(pA0 + 32 * (ks4 + 1) + 4);
            nx1 = *(const float4*)(pA1 + 32 * (ks4 + 1));
            ny1 = *(const float4*)(pA1 + 32 * (ks4 + 1) + 4);
        }
        half8v bfr[4];
        #pragma unroll
        for (int cf = 0; cf < 4; ++cf)
            bfr[cf] = *(const half8v*)&Bs[(((size_t)(ks4 * 4 + cf) * 64) + lane) * 8];
        half8v a0 = cvt8(cx0, cy0);
        half8v a1 = cvt8(cx1, cy1);
        #pragma unroll
        for (int cf = 0; cf < 4; ++cf) {
            acc[0][cf] = __builtin_amdgcn_mfma_f32_16x16x32_f16(a0, bfr[cf], acc[0][cf], 0, 0, 0);
            acc[1][cf] = __builtin_amdgcn_mfma_f32_16x16x32_f16(a1, bfr[cf], acc[1][cf], 0, 0, 0);
        }
    }

    #pragma unroll
    for (int rf = 0; rf < 2; ++rf) {
        #pragma unroll
        for (int r = 0; r < 4; ++r) {
            int row = rw0 + rf * 16 + l4 * 4 + r;
            if (row < N_NODES) {
                float s = norm_out[row];
                #pragma unroll
                for (int cf = 0; cf < 4; ++cf)
                    h[(size_t)row * OUT_F + cf * 16 + l15] = f2bf(acc[rf][cf][r] * s);
            }
        }
    }
}

// --- aggregate: one wave per dst node; 32 edges per iteration via FOUR independent
//     id-load + uint4-gather chains (deep MLP).  Branchless clamp+mask. ---
__global__ __launch_bounds__(256) void agg_kernel(const int* __restrict__ row_ptr,
                                                  const unsigned* __restrict__ edge_src,
                                                  const unsigned short* __restrict__ h,
                                                  const float* __restrict__ bias,
                                                  float* __restrict__ out) {
    int wid  = (blockIdx.x * 256 + threadIdx.x) >> 6;
    int lane = threadIdx.x & 63;
    if (wid >= N_NODES) return;
    int g  = lane >> 3;
    int fp = lane & 7;
    int start = row_ptr[wid];
    int end   = row_ptr[wid + 1];
    int deg   = end - start;

    float a[8];
    #pragma unroll
    for (int i = 0; i < 8; ++i) a[i] = 0.f;

    for (int e = start; e < end; e += 32) {
        int ee0 = e + g, ee1 = ee0 + 8, ee2 = ee0 + 16, ee3 = ee0 + 24;
        int id0 = (ee0 < end) ? (int)edge_src[ee0] : -1;
        int id1 = (ee1 < end) ? (int)edge_src[ee1] : -1;
        int id2 = (ee2 < end) ? (int)edge_src[ee2] : -1;
        int id3 = (ee3 < end) ? (int)edge_src[ee3] : -1;
        int s0 = id0 >= 0 ? id0 : 0;
        int s1 = id1 >= 0 ? id1 : 0;
        int s2 = id2 >= 0 ? id2 : 0;
        int s3 = id3 >= 0 ? id3 : 0;
        uint4 w0 = *(const uint4*)&h[(size_t)s0 * OUT_F + fp * 8];
        uint4 w1 = *(const uint4*)&h[(size_t)s1 * OUT_F + fp * 8];
        uint4 w2 = *(const uint4*)&h[(size_t)s2 * OUT_F + fp * 8];
        uint4 w3 = *(const uint4*)&h[(size_t)s3 * OUT_F + fp * 8];
        if (id0 < 0) { w0.x = 0u; w0.y = 0u; w0.z = 0u; w0.w = 0u; }
        if (id1 < 0) { w1.x = 0u; w1.y = 0u; w1.z = 0u; w1.w = 0u; }
        if (id2 < 0) { w2.x = 0u; w2.y = 0u; w2.z = 0u; w2.w = 0u; }
        if (id3 < 0) { w3.x = 0u; w3.y = 0u; w3.z = 0u; w3.w = 0u; }
        a[0] += bf2f(w0.x & 0xFFFFu); a[1] += bf2f(w0.x >> 16);
        a[2] += bf2f(w0.y & 0xFFFFu); a[3] += bf2f(w0.y >> 16);
        a[4] += bf2f(w0.z & 0xFFFFu); a[5] += bf2f(w0.z >> 16);
        a[6] += bf2f(w0.w & 0xFFFFu); a[7] += bf2f(w0.w >> 16);
        a[0] += bf2f(w1.x & 0xFFFFu); a[1] += bf2f(w1.x >> 16);
        a[2] += bf2f(w1.y & 0xFFFFu); a[3] += bf2f(w1.y >> 16);
        a[4] += bf2f(w1.z & 0xFFFFu); a[5] += bf2f(w1.z >> 16);
        a[6] += bf2f(w1.w & 0xFFFFu); a[7] += bf2f(w1.w >> 16);
        a[0] += bf2f(w2.x & 0xFFFFu); a[1] += bf2f(w2.x >> 16);
        a[2] += bf2f(w2.y & 0xFFFFu); a[3] += bf2f(w2.y >> 16);
        a[4] += bf2f(w2.z & 0xFFFFu); a[5] += bf2f(w2.z >> 16);
        a[6] += bf2f(w2.w & 0xFFFFu); a[7] += bf2f(w2.w >> 16);
        a[0] += bf2f(w3.x & 0xFFFFu); a[1] += bf2f(w3.x >> 16);
        a[2] += bf2f(w3.y & 0xFFFFu); a[3] += bf2f(w3.y >> 16);
        a[4] += bf2f(w3.z & 0xFFFFu); a[5] += bf2f(w3.z >> 16);
        a[6] += bf2f(w3.w & 0xFFFFu); a[7] += bf2f(w3.w >> 16);
    }

    #pragma unroll
    for (int off = 8; off < 64; off <<= 1) {
        #pragma unroll
        for (int i = 0; i < 8; ++i) a[i] += __shfl_xor(a[i], off);
    }

    if (g == 0) {
        int dc = deg < 1 ? 1 : deg;
        float nrm = rsqrtf((float)dc);
        float4 b0 = *(const float4*)&bias[fp * 8];
        float4 b1 = *(const float4*)&bias[fp * 8 + 4];
        float4 r0, r1;
        r0.x = fmaxf(a[0] * nrm + b0.x, 0.f);
        r0.y = fmaxf(a[1] * nrm + b0.y, 0.f);
        r0.z = fmaxf(a[2] * nrm + b0.z, 0.f);
        r0.w = fmaxf(a[3] * nrm + b0.w, 0.f);
        r1.x = fmaxf(a[4] * nrm + b1.x, 0.f);
        r1.y = fmaxf(a[5] * nrm + b1.y, 0.f);
        r1.z = fmaxf(a[6] * nrm + b1.z, 0.f);
        r1.w = fmaxf(a[7] * nrm + b1.w, 0.f);
        *(float4*)&out[(size_t)wid * OUT_F + fp * 8]     = r0;
        *(float4*)&out[(size_t)wid * OUT_F + fp * 8 + 4] = r1;
    }
}

extern "C" void kernel_launch(void* const* d_in, const int* in_sizes, int n_in,
                              void* d_out, int out_size, void* d_ws, size_t ws_size,
                              hipStream_t stream) {
    const float* feat = (const float*)d_in[0];
    const float* W    = (const float*)d_in[1];
    const float* bias = (const float*)d_in[2];
    const int*   src  = (const int*)d_in[3];
    const int*   dst  = (const int*)d_in[4];
    float* out = (float*)d_out;

    char* w = (char*)d_ws;
    size_t off = 0;
    auto take = [&](size_t bytes) { char* p = w + off; off += (bytes + 255) & ~(size_t)255; return p; };

    int*            hist_g   = (int*)take((size_t)MSIZE * 4);
    int*            partials = (int*)take((size_t)SC_BLOCKS * 4);
    float*          norm_out = (float*)take((size_t)NPAD * 4);
    int*            row_ptr  = (int*)take((size_t)(NPAD + 64) * 4);
    _Float16*       Wt2      = (_Float16*)take((size_t)IN_F * OUT_F * 2);   // 32 KB
    unsigned*       edge_buf = (unsigned*)take((size_t)N_EDGES * 4);
    unsigned short* h        = (unsigned short*)take((size_t)NPAD * OUT_F * 2);
    int*            src_part = (int*)take((size_t)N_EDGES * 4);

    histA_kernel<<<NBLK, 256, 0, stream>>>(src, dst, hist_g, W, Wt2);
    scan1_kernel<<<SC_BLOCKS, 256, 0, stream>>>(hist_g, partials);
    scan2_kernel<<<1, 1024, 0, stream>>>(partials);
    part_kernel<<<NBLK, 256, 0, stream>>>(src, dst, hist_g, partials, edge_buf, src_part);
    bucket_kernel<<<NB, 256, 0, stream>>>(edge_buf, hist_g, partials, row_ptr, src_part, norm_out);
    gemm_kernel<<<(NPAD / 128), 256, 0, stream>>>(feat, Wt2, norm_out, h);
    agg_kernel<<<(N_NODES * 64 + 255) / 256, 256, 0, stream>>>(row_ptr, edge_buf, h, bias, out);
}